// Round 21
// baseline (400.001 us; speedup 1.0000x reference)
//
#include <hip/hip_runtime.h>
#include <hip/hip_bf16.h>

#define N_NODES 50000
#define N_EDGES 1600000
#define N_CAND  1000
#define N_GRAPHS 50
#define EMB 32
#define L_LAYERS 4

#define BSH 8
#define BNODES 256
#define NBK ((N_NODES + BNODES - 1) >> BSH)    // 196 buckets of 256 nodes
#define STILE 4096
#define NBLK_S ((N_EDGES + STILE - 1) / STILE) // 391

#define NPW 8  // nodes per wave (4 pairs); 50000 % 8 == 0 -> 6250 full waves

#define W1A_OFF 0
#define W1B_OFF 4096
#define W2_OFF  8192
#define WE_OFF  12288
#define C1_OFF  12416
#define C2_OFF  12544
#define W2H_OFF  12672   // f16[4][1024] = 2048 floats
#define WEH_OFF  14720   // f16[4][32]   = 64 floats
#define W1AH_OFF 14784   // f16[4][1024] = 2048 floats
#define W1BH_OFF 16832   // f16[4][1024] = 2048 floats
#define H_OFF    18880
#define NODE_F  (N_NODES * EMB)

// float-indexed: h0, h1 (fp32, NODE_F each), hA0/hB0 (f16, NODE_F floats),
//                hA1/hB1 (f16, NODE_F floats)
#define BH_OFF    (H_OFF + 4 * NODE_F)                   // int[NBK]
#define BOFF_OFF  (BH_OFF + NBK)                         // int[NBK+1]
#define OFFS_OFF  (BOFF_OFF + NBK + 1)                   // int[N_NODES+1]
#define CSR_OFF   (OFFS_OFF + N_NODES + 1)               // int[N_EDGES] (src|f16ea<<16)
#define T_OFF     (CSR_OFF + N_EDGES)                    // int[NBK*NBLK_S]
// stage (int2[N_EDGES] = 2*NODE_F floats) aliases [h1, hA0/hB0] (pre-embed only)

typedef float f32x4 __attribute__((ext_vector_type(4)));
typedef _Float16 f16x8 __attribute__((ext_vector_type(8)));

union HU { unsigned short u; _Float16 f; };
static __device__ __forceinline__ _Float16 h16(unsigned short u) { HU c; c.u = u; return c.f; }
static __device__ __forceinline__ unsigned short u16(_Float16 f) { HU c; c.f = f; return c.u; }

// fused: blocks 0..3 fold layer-l weights (threads 0..255), ALL blocks histogram.
__global__ void prep_bhist_k(const float* __restrict__ W1, const float* __restrict__ b1,
                             const float* __restrict__ g1, const float* __restrict__ be1,
                             const float* __restrict__ m1, const float* __restrict__ v1,
                             const float* __restrict__ W2, const float* __restrict__ b2,
                             const float* __restrict__ g2, const float* __restrict__ be2,
                             const float* __restrict__ m2, const float* __restrict__ v2,
                             float* __restrict__ ws,
                             const int* __restrict__ ei, int* __restrict__ T) {
    if (blockIdx.x < L_LAYERS && threadIdx.x < 256) {
        int t = threadIdx.x;
        int l = blockIdx.x;
        _Float16* W2H  = (_Float16*)(ws + W2H_OFF);
        _Float16* WEH  = (_Float16*)(ws + WEH_OFF);
        _Float16* W1AH = (_Float16*)(ws + W1AH_OFF);
        _Float16* W1BH = (_Float16*)(ws + W1BH_OFF);
        for (int i = t; i < 1024; i += 256) {
            int k = i >> 5, j = i & 31;
            float s1 = g1[l * 32 + j] * rsqrtf(v1[l * 32 + j] + 1e-5f);
            float s2 = g2[l * 32 + j] * rsqrtf(v2[l * 32 + j] + 1e-5f);
            float wa = W1[(l * 65 + k) * 32 + j] * s1;
            float wb = W1[(l * 65 + 32 + k) * 32 + j] * s1;
            ws[W1A_OFF + l * 1024 + i] = wa;
            ws[W1B_OFF + l * 1024 + i] = wb;
            W1AH[l * 1024 + i] = (_Float16)wa;
            W1BH[l * 1024 + i] = (_Float16)wb;
            float w2v = W2[(l * 32 + k) * 32 + j] * s2;
            ws[W2_OFF + l * 1024 + i] = w2v;
            W2H[l * 1024 + i] = (_Float16)w2v;
            if (k == 0) {
                float wev = W1[(l * 65 + 64) * 32 + j] * s1;
                ws[WE_OFF + l * 32 + j] = wev;
                WEH[l * 32 + j] = (_Float16)wev;
                ws[C1_OFF + l * 32 + j] = b1[l * 32 + j] * s1 + be1[l * 32 + j] - m1[l * 32 + j] * s1;
                ws[C2_OFF + l * 32 + j] = b2[l * 32 + j] * s2 + be2[l * 32 + j] - m2[l * 32 + j] * s2;
            }
        }
    }
    // histogram phase (all 512 threads, all blocks)
    __shared__ int lh[NBK];
    for (int i = threadIdx.x; i < NBK; i += 512) lh[i] = 0;
    __syncthreads();
    int tb = blockIdx.x * STILE;
#pragma unroll
    for (int i = 0; i < STILE / 512; ++i) {
        int e = tb + i * 512 + threadIdx.x;
        if (e < N_EDGES) atomicAdd(&lh[ei[N_EDGES + e] >> BSH], 1);
    }
    __syncthreads();
    for (int i = threadIdx.x; i < NBK; i += 512)
        T[i * NBLK_S + blockIdx.x] = lh[i];
}

// fused: h0 = x@Win+bin ; hA/hB for layer 0 (fp32 matvec, f16 store)
__global__ void embed_node_k(const float* __restrict__ x, const float* __restrict__ Win,
                             const float* __restrict__ bin, const float* __restrict__ ws,
                             float* __restrict__ h, _Float16* __restrict__ hA,
                             _Float16* __restrict__ hB) {
    __shared__ float sA[1024], sB[1024];
    for (int i = threadIdx.x; i < 1024; i += blockDim.x) {
        sA[i] = ws[W1A_OFF + i];
        sB[i] = ws[W1B_OFF + i];
    }
    __syncthreads();
    int t = blockIdx.x * blockDim.x + threadIdx.x;
    if (t >= NODE_F) return;
    int n = t >> 5, j = t & 31;
    float hv = x[2 * n] * Win[j] + x[2 * n + 1] * Win[32 + j] + bin[j];
    h[t] = hv;
    float a = ws[C1_OFF + j];
    float b = 0.f;
#pragma unroll
    for (int k = 0; k < 32; ++k) {
        float hk = __shfl(hv, k, 32);
        a += hk * sA[k * 32 + j];
        b += hk * sB[k * 32 + j];
    }
    hA[t] = (_Float16)a;
    hB[t] = (_Float16)b;
}

// one block per bucket: exclusive scan of T[k][*] -> RELATIVE offsets; row total -> bh[k]
__global__ void bcursor_k(int* __restrict__ T, int* __restrict__ bh) {
    __shared__ int part[1024];
    int k = blockIdx.x, t = threadIdx.x;
    int v = (t < NBLK_S) ? T[k * NBLK_S + t] : 0;
    part[t] = v;
    __syncthreads();
    for (int d = 1; d < 1024; d <<= 1) {
        int u = (t >= d) ? part[t - d] : 0;
        __syncthreads();
        part[t] += u;
        __syncthreads();
    }
    if (t < NBLK_S) T[k * NBLK_S + t] = part[t] - v;   // relative exclusive prefix
    if (t == 1023) bh[k] = part[t];                    // row total
}

// single block: exclusive scan of bh[NBK] -> boffs
__global__ void bscan_k(const int* __restrict__ bh, int* __restrict__ boffs) {
    __shared__ int part[1024];
    int t = threadIdx.x;
    int s = (t < NBK) ? bh[t] : 0;
    part[t] = s;
    __syncthreads();
    for (int d = 1; d < 1024; d <<= 1) {
        int v = (t >= d) ? part[t - d] : 0;
        __syncthreads();
        part[t] += v;
        __syncthreads();
    }
    if (t < NBK) boffs[t] = part[t] - s;
    if (t == 1023) boffs[NBK] = N_EDGES;
}

// binning: cursors = boffs[bucket] + relative T; one read pass, LDS cursor alloc, int2 write
__global__ void bscatter_k(const int* __restrict__ ei, const float* __restrict__ ea,
                           const int* __restrict__ T, const int* __restrict__ boffs,
                           int2* __restrict__ stage) {
    __shared__ int lofs[NBK];
    for (int i = threadIdx.x; i < NBK; i += 512)
        lofs[i] = boffs[i] + T[i * NBLK_S + blockIdx.x];
    __syncthreads();
    int tb = blockIdx.x * STILE;
#pragma unroll
    for (int i = 0; i < STILE / 512; ++i) {
        int e = tb + i * 512 + threadIdx.x;
        if (e < N_EDGES) {
            int src = ei[e], dst = ei[N_EDGES + e];
            int bk = dst >> BSH;
            int pos = atomicAdd(&lofs[bk], 1);
            int2 p;
            p.x = src | ((dst & (BNODES - 1)) << 16);
            p.y = __float_as_int(ea[e]);
            stage[pos] = p;
        }
    }
}

// one block per 256-node bucket: hist + wave-scan prefix -> offs[n]; exact scatter.
// csr entry packed as src(16b) | f16(ea)(16b).
__global__ void bsort2_k(const int* __restrict__ boffs, const int2* __restrict__ stage,
                         int* __restrict__ offs, int* __restrict__ csr) {
    __shared__ int cnt[BNODES];
    __shared__ int pre[BNODES];
    __shared__ int cur[BNODES];
    const int b = blockIdx.x;
    const int nbase = b << BSH;
    const int t = threadIdx.x;  // 512
    const int beg = boffs[b], end = boffs[b + 1];
    if (t < BNODES) cnt[t] = 0;
    __syncthreads();
    for (int i = beg + t; i < end; i += 512)
        atomicAdd(&cnt[(stage[i].x >> 16) & (BNODES - 1)], 1);
    __syncthreads();
    if (t < 64) {
        int b4 = t * 4;
        int c0 = cnt[b4], c1 = cnt[b4 + 1], c2 = cnt[b4 + 2], c3 = cnt[b4 + 3];
        int s = c0 + c1 + c2 + c3;
        int run = s;
#pragma unroll
        for (int d = 1; d < 64; d <<= 1) {
            int v = __shfl_up(run, d, 64);
            if (t >= d) run += v;
        }
        int ex = run - s;  // exclusive
        pre[b4] = ex; pre[b4 + 1] = ex + c0; pre[b4 + 2] = ex + c0 + c1; pre[b4 + 3] = ex + c0 + c1 + c2;
    }
    __syncthreads();
    if (t < BNODES) {
        cur[t] = pre[t];
        int n = nbase + t;
        if (n < N_NODES) offs[n] = beg + pre[t];
    }
    if (b == NBK - 1 && t == 0) offs[N_NODES] = N_EDGES;
    __syncthreads();
    for (int i = beg + t; i < end; i += 512) {
        int2 p = stage[i];
        int dloc = (p.x >> 16) & (BNODES - 1);
        int pos = beg + atomicAdd(&cur[dloc], 1);
        unsigned short eh = u16((_Float16)__int_as_float(p.y));
        csr[pos] = (p.x & 0xFFFF) | ((int)eh << 16);
    }
}

// ---------------- fused per-layer kernel (R20 structure, occupancy 4->6) ----------------
// One wave = 8 nodes (4 pairs). Cross-pair software pipeline: all offs scalar-loaded,
// all 8 chunk-0 csr loads + 8 hB gathers + 8 chunk-1 csr loads issued BEFORE pair-0
// computes. fp16 MFMA edge math with C2 in the C-operand; s_setprio(1) around the
// per-chunk compute cluster; per-wave XOR-swizzled LDS stash + 4-MFMA epilogue.
// launch_bounds(256,6): grid is 6.1 blocks/CU; the old cap of 4 clipped residency.
__launch_bounds__(256, 6)
__global__ void edge_mfma_k(const int* __restrict__ offs, const int* __restrict__ csr,
                            const float* __restrict__ ws, int l,
                            const float* __restrict__ h, const _Float16* __restrict__ hA,
                            const _Float16* __restrict__ hB, float* __restrict__ hnext,
                            _Float16* __restrict__ hAout, _Float16* __restrict__ hBout,
                            int doNext) {
    __shared__ float vbuf[4 * 256];   // per-wave [8 nodes][32 ch], XOR-swizzled
    const int lane = threadIdx.x & 63;
    const int wid = (blockIdx.x * 256 + threadIdx.x) >> 6;
    const int r = lane & 15;   // A row (edge slot) / D col (channel)
    const int q = lane >> 4;   // channel octet / D row quad
    const int ll = lane & 31;
    float* vb = vbuf + (threadIdx.x >> 6) * 256;
    const int nbase = wid * NPW;
    if (nbase >= N_NODES) return;   // 50000 % 8 == 0 -> full waves only

    // wave-uniform segment bounds -> SGPRs
    int o[NPW + 1];
#pragma unroll
    for (int i = 0; i <= NPW; ++i)
        o[i] = __builtin_amdgcn_readfirstlane(offs[nbase + i]);

    const _Float16* W2H = (const _Float16*)(ws + W2H_OFF);
    f16x8 b0, b1;
#pragma unroll
    for (int i = 0; i < 8; ++i) {
        b0[i] = W2H[l * 1024 + (8 * q + i) * 32 + r];
        b1[i] = W2H[l * 1024 + (8 * q + i) * 32 + 16 + r];
    }
    const float c2a = ws[C2_OFF + l * 32 + r];
    const float c2b = ws[C2_OFF + l * 32 + 16 + r];
    const f32x4 zc0 = {c2a, c2a, c2a, c2a};
    const f32x4 zc1 = {c2b, c2b, c2b, c2b};
    const f16x8 we = *(const f16x8*)((const _Float16*)(ws + WEH_OFF) + l * 32 + 8 * q);
    const f16x8 zero8 = {};

#define CEI(EB, LIM) ({ int _e = (EB) + r; _e = (_e < (LIM)) ? _e : (LIM); _e = (_e > 0) ? _e : 0; _e; })

    // prologue: issue chunk-0 csr, chunk-0 gathers, chunk-1 csr for ALL 4 pairs
    int lim[NPW];
#pragma unroll
    for (int s = 0; s < NPW; ++s) {
        int e1 = o[s + 1] - 1;
        lim[s] = (e1 > 0) ? e1 : 0;
    }
    int pc[NPW], pn[NPW];
#pragma unroll
    for (int s = 0; s < NPW; ++s) pc[s] = csr[CEI(o[s], lim[s])];
    f16x8 hc[NPW];
#pragma unroll
    for (int s = 0; s < NPW; ++s)
        hc[s] = *(const f16x8*)(hB + (pc[s] & 0xFFFF) * 32 + 8 * q);
#pragma unroll
    for (int s = 0; s < NPW; ++s) pn[s] = csr[CEI(o[s] + 16, lim[s])];

#pragma unroll
    for (int p = 0; p < 4; ++p) {
        const int s0 = 2 * p, s1 = 2 * p + 1;
        const int n0 = nbase + s0;
        const int n1 = n0 + 1;
        const int o0 = o[s0], o1 = o[s1], o2 = o[s1 + 1];

        const f16x8 hA0 = *(const f16x8*)(hA + n0 * 32 + 8 * q);
        const f16x8 hA1 = *(const f16x8*)(hA + n1 * 32 + 8 * q);

        float ns00 = 0.f, ns01 = 0.f, ns10 = 0.f, ns11 = 0.f;
        int nit = (o1 - o0 + 15) >> 4;
        int nit1 = (o2 - o1 + 15) >> 4;
        if (nit1 > nit) nit = nit1;

        if (nit > 0) {
            const int lim0 = lim[s0], lim1 = lim[s1];
            int eb0 = o0, eb1 = o1;
            int pc0 = pc[s0], pc1 = pc[s1];
            f16x8 hc0 = hc[s0], hc1 = hc[s1];
            int pn0 = pn[s0], pn1 = pn[s1];
            for (int it = 0; it < nit; ++it) {
                f16x8 hn0 = *(const f16x8*)(hB + (pn0 & 0xFFFF) * 32 + 8 * q);
                f16x8 hn1 = *(const f16x8*)(hB + (pn1 & 0xFFFF) * 32 + 8 * q);
                int pm0 = csr[CEI(eb0 + 32, lim0)];
                int pm1 = csr[CEI(eb1 + 32, lim1)];
                __builtin_amdgcn_s_setprio(1);
                _Float16 eah0 = h16((unsigned short)((unsigned)pc0 >> 16));
                _Float16 eah1 = h16((unsigned short)((unsigned)pc1 >> 16));
                f16x8 a0 = __builtin_elementwise_max(we * eah0 + (hA0 + hc0), zero8);
                f16x8 a1 = __builtin_elementwise_max(we * eah1 + (hA1 + hc1), zero8);
                f32x4 acc00 = __builtin_amdgcn_mfma_f32_16x16x32_f16(a0, b0, zc0, 0, 0, 0);
                f32x4 acc01 = __builtin_amdgcn_mfma_f32_16x16x32_f16(a0, b1, zc1, 0, 0, 0);
                f32x4 acc10 = __builtin_amdgcn_mfma_f32_16x16x32_f16(a1, b0, zc0, 0, 0, 0);
                f32x4 acc11 = __builtin_amdgcn_mfma_f32_16x16x32_f16(a1, b1, zc1, 0, 0, 0);
                int nr0 = o1 - eb0;
                int nr1 = o2 - eb1;
#pragma unroll
                for (int reg = 0; reg < 4; ++reg) {
                    int row = 4 * q + reg;
                    float m0 = (row < nr0) ? 1.f : 0.f;
                    float m1 = (row < nr1) ? 1.f : 0.f;
                    ns00 = fmaf(m0, fmaxf(acc00[reg], 0.f), ns00);
                    ns01 = fmaf(m0, fmaxf(acc01[reg], 0.f), ns01);
                    ns10 = fmaf(m1, fmaxf(acc10[reg], 0.f), ns10);
                    ns11 = fmaf(m1, fmaxf(acc11[reg], 0.f), ns11);
                }
                __builtin_amdgcn_s_setprio(0);
                eb0 += 16; eb1 += 16;
                pc0 = pn0; pc1 = pn1;
                hc0 = hn0; hc1 = hn1;
                pn0 = pm0; pn1 = pm1;
            }
        }
        ns00 += __shfl_xor(ns00, 16, 64);
        ns00 += __shfl_xor(ns00, 32, 64);
        ns01 += __shfl_xor(ns01, 16, 64);
        ns01 += __shfl_xor(ns01, 32, 64);
        ns10 += __shfl_xor(ns10, 16, 64);
        ns10 += __shfl_xor(ns10, 32, 64);
        ns11 += __shfl_xor(ns11, 16, 64);
        ns11 += __shfl_xor(ns11, 32, 64);

        float v;
        if (lane < 32) {
            v = h[n0 * 32 + ll] + ((ll & 16) ? ns01 : ns00);
            hnext[n0 * 32 + ll] = v;
        } else {
            v = h[n1 * 32 + ll] + ((ll & 16) ? ns11 : ns10);
            hnext[n1 * 32 + ll] = v;
        }
        int node8 = s0 + (lane >> 5);                 // 0..7
        vb[node8 * 32 + (ll ^ (node8 << 2))] = v;     // XOR swizzle, conflict-free
    }
#undef CEI

    // epilogue: next layer's hA/hB via 4 MFMAs (wave-private LDS, in-order DS, no barrier)
    if (doNext) {
        const int lw = l + 1;
        f16x8 av;
#pragma unroll
        for (int i = 0; i < 8; ++i) {
            int rr = r & 7;
            int ch = 8 * q + i;
            float vv = vb[rr * 32 + (ch ^ (rr << 2))];
            av[i] = (r < 8) ? (_Float16)vv : (_Float16)0.f;
        }
        const _Float16* W1AH = (const _Float16*)(ws + W1AH_OFF) + lw * 1024;
        const _Float16* W1BH = (const _Float16*)(ws + W1BH_OFF) + lw * 1024;
        f16x8 wa0, wa1, wb0, wb1;
#pragma unroll
        for (int i = 0; i < 8; ++i) {
            wa0[i] = W1AH[(8 * q + i) * 32 + r];
            wa1[i] = W1AH[(8 * q + i) * 32 + 16 + r];
            wb0[i] = W1BH[(8 * q + i) * 32 + r];
            wb1[i] = W1BH[(8 * q + i) * 32 + 16 + r];
        }
        const float c1a = ws[C1_OFF + lw * 32 + r];
        const float c1b = ws[C1_OFF + lw * 32 + 16 + r];
        const f32x4 ca = {c1a, c1a, c1a, c1a};
        const f32x4 cb = {c1b, c1b, c1b, c1b};
        const f32x4 z4 = {0.f, 0.f, 0.f, 0.f};
        f32x4 dA0 = __builtin_amdgcn_mfma_f32_16x16x32_f16(av, wa0, ca, 0, 0, 0);
        f32x4 dA1 = __builtin_amdgcn_mfma_f32_16x16x32_f16(av, wa1, cb, 0, 0, 0);
        f32x4 dB0 = __builtin_amdgcn_mfma_f32_16x16x32_f16(av, wb0, z4, 0, 0, 0);
        f32x4 dB1 = __builtin_amdgcn_mfma_f32_16x16x32_f16(av, wb1, z4, 0, 0, 0);
#pragma unroll
        for (int reg = 0; reg < 4; ++reg) {
            int row = 4 * q + reg;   // node index within wave (valid 0..7)
            int n = nbase + row;
            if (row < 8 && n < N_NODES) {
                hAout[n * 32 + r]      = (_Float16)dA0[reg];
                hAout[n * 32 + 16 + r] = (_Float16)dA1[reg];
                hBout[n * 32 + r]      = (_Float16)dB0[reg];
                hBout[n * 32 + 16 + r] = (_Float16)dB1[reg];
            }
        }
    }
}

__global__ void head_k(const float* __restrict__ h, const int* __restrict__ cand,
                       const int* __restrict__ batch, const float* __restrict__ Wout,
                       const float* __restrict__ bout, float* __restrict__ out) {
    __shared__ float Lg[N_CAND];
    __shared__ int Sg[N_CAND];
    __shared__ float gm[N_GRAPHS], gs[N_GRAPHS];
    int t = threadIdx.x;  // 1024
    if (t < N_CAND) {
        int c = cand[t];
        float acc = bout[0];
#pragma unroll
        for (int j = 0; j < 32; ++j) acc += h[c * 32 + j] * Wout[j];
        Lg[t] = acc;
        Sg[t] = batch[c];
    }
    __syncthreads();
    if (t < 16 * N_GRAPHS) {
        int g = t >> 4, s = t & 15;
        float m = -1e30f;
        for (int i = s; i < N_CAND; i += 16)
            if (Sg[i] == g) m = fmaxf(m, Lg[i]);
#pragma unroll
        for (int d = 1; d < 16; d <<= 1) m = fmaxf(m, __shfl_xor(m, d, 64));
        float ssum = 0.f;
        for (int i = s; i < N_CAND; i += 16)
            if (Sg[i] == g) ssum += expf(Lg[i] - m);
#pragma unroll
        for (int d = 1; d < 16; d <<= 1) ssum += __shfl_xor(ssum, d, 64);
        if (s == 0) { gm[g] = m; gs[g] = logf(ssum); }
    }
    __syncthreads();
    if (t < N_CAND) out[t] = Lg[t] - gm[Sg[t]] - gs[Sg[t]];
}

extern "C" void kernel_launch(void* const* d_in, const int* in_sizes, int n_in,
                              void* d_out, int out_size, void* d_ws, size_t ws_size,
                              hipStream_t stream) {
    const float* x    = (const float*)d_in[0];
    const int*   ei   = (const int*)d_in[1];
    const float* eatt = (const float*)d_in[2];
    const int*   cand = (const int*)d_in[3];
    const int*   batch= (const int*)d_in[4];
    const float* Win  = (const float*)d_in[5];
    const float* bin  = (const float*)d_in[6];
    const float* W1   = (const float*)d_in[7];
    const float* b1   = (const float*)d_in[8];
    const float* g1   = (const float*)d_in[9];
    const float* be1  = (const float*)d_in[10];
    const float* m1   = (const float*)d_in[11];
    const float* v1   = (const float*)d_in[12];
    const float* W2   = (const float*)d_in[13];
    const float* b2   = (const float*)d_in[14];
    const float* g2   = (const float*)d_in[15];
    const float* be2  = (const float*)d_in[16];
    const float* m2   = (const float*)d_in[17];
    const float* v2   = (const float*)d_in[18];
    const float* Wout = (const float*)d_in[19];
    const float* bout = (const float*)d_in[20];
    float* out = (float*)d_out;
    float* ws = (float*)d_ws;

    float* h0 = ws + H_OFF;
    float* h1 = ws + H_OFF + NODE_F;
    _Float16* hA0 = (_Float16*)(ws + H_OFF + 2 * NODE_F);
    _Float16* hB0 = (_Float16*)(ws + H_OFF + 2 * NODE_F + NODE_F / 2);
    _Float16* hA1 = (_Float16*)(ws + H_OFF + 3 * NODE_F);
    _Float16* hB1 = (_Float16*)(ws + H_OFF + 3 * NODE_F + NODE_F / 2);
    int* bh    = (int*)(ws + BH_OFF);
    int* boffs = (int*)(ws + BOFF_OFF);
    int* offs  = (int*)(ws + OFFS_OFF);
    int* csr   = (int*)(ws + CSR_OFF);
    int* T     = (int*)(ws + T_OFF);
    int2* stage = (int2*)(ws + H_OFF + NODE_F);  // aliases h1+hA0/hB0 (pre-embed only)

    prep_bhist_k<<<NBLK_S, 512, 0, stream>>>(W1, b1, g1, be1, m1, v1,
                                             W2, b2, g2, be2, m2, v2, ws, ei, T);
    bcursor_k<<<NBK, 1024, 0, stream>>>(T, bh);
    bscan_k<<<1, 1024, 0, stream>>>(bh, boffs);
    bscatter_k<<<NBLK_S, 512, 0, stream>>>(ei, eatt, T, boffs, stage);
    bsort2_k<<<NBK, 512, 0, stream>>>(boffs, stage, offs, csr);

    // embed + layer-0 node transform (after stage's aliased region is consumed)
    embed_node_k<<<(NODE_F + 1023) / 1024, 1024, 0, stream>>>(x, Win, bin, ws, h0, hA0, hB0);

    const int waves = (N_NODES + NPW - 1) / NPW;       // 6250
    const int eblocks = (waves + 3) / 4;               // 1563
    float* cur = h0;
    float* nxt = h1;
    _Float16 *cA = hA0, *cB = hB0, *nA = hA1, *nB = hB1;
    for (int l = 0; l < L_LAYERS; ++l) {
        edge_mfma_k<<<eblocks, 256, 0, stream>>>(offs, csr, ws, l, cur, cA, cB,
                                                 nxt, nA, nB, l < L_LAYERS - 1);
        float* tf = cur; cur = nxt; nxt = tf;
        _Float16* t1 = cA; cA = nA; nA = t1;
        _Float16* t2 = cB; cB = nB; nB = t2;
    }

    head_k<<<1, 1024, 0, stream>>>(cur, cand, batch, Wout, bout, out);
}

// Round 22
// 201.686 us; speedup vs baseline: 1.9833x; 1.9833x over previous
//
#include <hip/hip_runtime.h>
#include <hip/hip_bf16.h>

#define N_NODES 50000
#define N_EDGES 1600000
#define N_CAND  1000
#define N_GRAPHS 50
#define EMB 32
#define L_LAYERS 4

#define BSH 8
#define BNODES 256
#define NBK ((N_NODES + BNODES - 1) >> BSH)    // 196 buckets of 256 nodes
#define STILE 4096
#define NBLK_S ((N_EDGES + STILE - 1) / STILE) // 391

#define NPW 8  // nodes per wave (4 pairs); 50000 % 8 == 0 -> 6250 full waves

#define W1A_OFF 0
#define W1B_OFF 4096
#define W2_OFF  8192
#define WE_OFF  12288
#define C1_OFF  12416
#define C2_OFF  12544
#define W2H_OFF  12672   // f16[4][1024] = 2048 floats
#define WEH_OFF  14720   // f16[4][32]   = 64 floats
#define W1AH_OFF 14784   // f16[4][1024] = 2048 floats
#define W1BH_OFF 16832   // f16[4][1024] = 2048 floats
#define H_OFF    18880
#define NODE_F  (N_NODES * EMB)

// float-indexed: h0, h1 (fp32, NODE_F each), hA0/hB0 (f16, NODE_F floats),
//                hA1/hB1 (f16, NODE_F floats)
#define BH_OFF    (H_OFF + 4 * NODE_F)                   // int[NBK]
#define BOFF_OFF  (BH_OFF + NBK)                         // int[NBK+1]
#define OFFS_OFF  (BOFF_OFF + NBK + 1)                   // int[N_NODES+1]
#define CSR_OFF   (OFFS_OFF + N_NODES + 1)               // int[N_EDGES] (src|f16ea<<16)
#define T_OFF     (CSR_OFF + N_EDGES)                    // int[NBK*NBLK_S]
// stage (int2[N_EDGES] = 2*NODE_F floats) aliases [h1, hA0/hB0] (pre-embed only)

typedef float f32x4 __attribute__((ext_vector_type(4)));
typedef _Float16 f16x8 __attribute__((ext_vector_type(8)));

union HU { unsigned short u; _Float16 f; };
static __device__ __forceinline__ _Float16 h16(unsigned short u) { HU c; c.u = u; return c.f; }
static __device__ __forceinline__ unsigned short u16(_Float16 f) { HU c; c.f = f; return c.u; }

// fused: blocks 0..3 fold layer-l weights (threads 0..255), ALL blocks histogram.
__global__ void prep_bhist_k(const float* __restrict__ W1, const float* __restrict__ b1,
                             const float* __restrict__ g1, const float* __restrict__ be1,
                             const float* __restrict__ m1, const float* __restrict__ v1,
                             const float* __restrict__ W2, const float* __restrict__ b2,
                             const float* __restrict__ g2, const float* __restrict__ be2,
                             const float* __restrict__ m2, const float* __restrict__ v2,
                             float* __restrict__ ws,
                             const int* __restrict__ ei, int* __restrict__ T) {
    if (blockIdx.x < L_LAYERS && threadIdx.x < 256) {
        int t = threadIdx.x;
        int l = blockIdx.x;
        _Float16* W2H  = (_Float16*)(ws + W2H_OFF);
        _Float16* WEH  = (_Float16*)(ws + WEH_OFF);
        _Float16* W1AH = (_Float16*)(ws + W1AH_OFF);
        _Float16* W1BH = (_Float16*)(ws + W1BH_OFF);
        for (int i = t; i < 1024; i += 256) {
            int k = i >> 5, j = i & 31;
            float s1 = g1[l * 32 + j] * rsqrtf(v1[l * 32 + j] + 1e-5f);
            float s2 = g2[l * 32 + j] * rsqrtf(v2[l * 32 + j] + 1e-5f);
            float wa = W1[(l * 65 + k) * 32 + j] * s1;
            float wb = W1[(l * 65 + 32 + k) * 32 + j] * s1;
            ws[W1A_OFF + l * 1024 + i] = wa;
            ws[W1B_OFF + l * 1024 + i] = wb;
            W1AH[l * 1024 + i] = (_Float16)wa;
            W1BH[l * 1024 + i] = (_Float16)wb;
            float w2v = W2[(l * 32 + k) * 32 + j] * s2;
            ws[W2_OFF + l * 1024 + i] = w2v;
            W2H[l * 1024 + i] = (_Float16)w2v;
            if (k == 0) {
                float wev = W1[(l * 65 + 64) * 32 + j] * s1;
                ws[WE_OFF + l * 32 + j] = wev;
                WEH[l * 32 + j] = (_Float16)wev;
                ws[C1_OFF + l * 32 + j] = b1[l * 32 + j] * s1 + be1[l * 32 + j] - m1[l * 32 + j] * s1;
                ws[C2_OFF + l * 32 + j] = b2[l * 32 + j] * s2 + be2[l * 32 + j] - m2[l * 32 + j] * s2;
            }
        }
    }
    // histogram phase (all 512 threads, all blocks)
    __shared__ int lh[NBK];
    for (int i = threadIdx.x; i < NBK; i += 512) lh[i] = 0;
    __syncthreads();
    int tb = blockIdx.x * STILE;
#pragma unroll
    for (int i = 0; i < STILE / 512; ++i) {
        int e = tb + i * 512 + threadIdx.x;
        if (e < N_EDGES) atomicAdd(&lh[ei[N_EDGES + e] >> BSH], 1);
    }
    __syncthreads();
    for (int i = threadIdx.x; i < NBK; i += 512)
        T[i * NBLK_S + blockIdx.x] = lh[i];
}

// fused: h0 = x@Win+bin ; hA/hB for layer 0 (fp32 matvec, f16 store)
__global__ void embed_node_k(const float* __restrict__ x, const float* __restrict__ Win,
                             const float* __restrict__ bin, const float* __restrict__ ws,
                             float* __restrict__ h, _Float16* __restrict__ hA,
                             _Float16* __restrict__ hB) {
    __shared__ float sA[1024], sB[1024];
    for (int i = threadIdx.x; i < 1024; i += blockDim.x) {
        sA[i] = ws[W1A_OFF + i];
        sB[i] = ws[W1B_OFF + i];
    }
    __syncthreads();
    int t = blockIdx.x * blockDim.x + threadIdx.x;
    if (t >= NODE_F) return;
    int n = t >> 5, j = t & 31;
    float hv = x[2 * n] * Win[j] + x[2 * n + 1] * Win[32 + j] + bin[j];
    h[t] = hv;
    float a = ws[C1_OFF + j];
    float b = 0.f;
#pragma unroll
    for (int k = 0; k < 32; ++k) {
        float hk = __shfl(hv, k, 32);
        a += hk * sA[k * 32 + j];
        b += hk * sB[k * 32 + j];
    }
    hA[t] = (_Float16)a;
    hB[t] = (_Float16)b;
}

// one block per bucket: exclusive scan of T[k][*] -> RELATIVE offsets; row total -> bh[k]
__global__ void bcursor_k(int* __restrict__ T, int* __restrict__ bh) {
    __shared__ int part[1024];
    int k = blockIdx.x, t = threadIdx.x;
    int v = (t < NBLK_S) ? T[k * NBLK_S + t] : 0;
    part[t] = v;
    __syncthreads();
    for (int d = 1; d < 1024; d <<= 1) {
        int u = (t >= d) ? part[t - d] : 0;
        __syncthreads();
        part[t] += u;
        __syncthreads();
    }
    if (t < NBLK_S) T[k * NBLK_S + t] = part[t] - v;   // relative exclusive prefix
    if (t == 1023) bh[k] = part[t];                    // row total
}

// single block: exclusive scan of bh[NBK] -> boffs
__global__ void bscan_k(const int* __restrict__ bh, int* __restrict__ boffs) {
    __shared__ int part[1024];
    int t = threadIdx.x;
    int s = (t < NBK) ? bh[t] : 0;
    part[t] = s;
    __syncthreads();
    for (int d = 1; d < 1024; d <<= 1) {
        int v = (t >= d) ? part[t - d] : 0;
        __syncthreads();
        part[t] += v;
        __syncthreads();
    }
    if (t < NBK) boffs[t] = part[t] - s;
    if (t == 1023) boffs[NBK] = N_EDGES;
}

// binning: cursors = boffs[bucket] + relative T; one read pass, LDS cursor alloc, int2 write
__global__ void bscatter_k(const int* __restrict__ ei, const float* __restrict__ ea,
                           const int* __restrict__ T, const int* __restrict__ boffs,
                           int2* __restrict__ stage) {
    __shared__ int lofs[NBK];
    for (int i = threadIdx.x; i < NBK; i += 512)
        lofs[i] = boffs[i] + T[i * NBLK_S + blockIdx.x];
    __syncthreads();
    int tb = blockIdx.x * STILE;
#pragma unroll
    for (int i = 0; i < STILE / 512; ++i) {
        int e = tb + i * 512 + threadIdx.x;
        if (e < N_EDGES) {
            int src = ei[e], dst = ei[N_EDGES + e];
            int bk = dst >> BSH;
            int pos = atomicAdd(&lofs[bk], 1);
            int2 p;
            p.x = src | ((dst & (BNODES - 1)) << 16);
            p.y = __float_as_int(ea[e]);
            stage[pos] = p;
        }
    }
}

// one block per 256-node bucket: hist + wave-scan prefix -> offs[n]; exact scatter.
// csr entry packed as src(16b) | f16(ea)(16b).
__global__ void bsort2_k(const int* __restrict__ boffs, const int2* __restrict__ stage,
                         int* __restrict__ offs, int* __restrict__ csr) {
    __shared__ int cnt[BNODES];
    __shared__ int pre[BNODES];
    __shared__ int cur[BNODES];
    const int b = blockIdx.x;
    const int nbase = b << BSH;
    const int t = threadIdx.x;  // 512
    const int beg = boffs[b], end = boffs[b + 1];
    if (t < BNODES) cnt[t] = 0;
    __syncthreads();
    for (int i = beg + t; i < end; i += 512)
        atomicAdd(&cnt[(stage[i].x >> 16) & (BNODES - 1)], 1);
    __syncthreads();
    if (t < 64) {
        int b4 = t * 4;
        int c0 = cnt[b4], c1 = cnt[b4 + 1], c2 = cnt[b4 + 2], c3 = cnt[b4 + 3];
        int s = c0 + c1 + c2 + c3;
        int run = s;
#pragma unroll
        for (int d = 1; d < 64; d <<= 1) {
            int v = __shfl_up(run, d, 64);
            if (t >= d) run += v;
        }
        int ex = run - s;  // exclusive
        pre[b4] = ex; pre[b4 + 1] = ex + c0; pre[b4 + 2] = ex + c0 + c1; pre[b4 + 3] = ex + c0 + c1 + c2;
    }
    __syncthreads();
    if (t < BNODES) {
        cur[t] = pre[t];
        int n = nbase + t;
        if (n < N_NODES) offs[n] = beg + pre[t];
    }
    if (b == NBK - 1 && t == 0) offs[N_NODES] = N_EDGES;
    __syncthreads();
    for (int i = beg + t; i < end; i += 512) {
        int2 p = stage[i];
        int dloc = (p.x >> 16) & (BNODES - 1);
        int pos = beg + atomicAdd(&cur[dloc], 1);
        unsigned short eh = u16((_Float16)__int_as_float(p.y));
        csr[pos] = (p.x & 0xFFFF) | ((int)eh << 16);
    }
}

// ---------------- fused per-layer kernel (R20 structure, validated best) ----------------
// One wave = 8 nodes (4 pairs). Cross-pair software pipeline: all offs scalar-loaded,
// all 8 chunk-0 csr loads + 8 hB gathers + 8 chunk-1 csr loads issued BEFORE pair-0
// computes. fp16 MFMA edge math with C2 in the C-operand; s_setprio(1) around the
// per-chunk compute cluster; per-wave XOR-swizzled LDS stash + 4-MFMA epilogue.
// launch_bounds(256,4): bound of 6 forces VGPR cap -> scratch spill (R21: 2x regression).
__launch_bounds__(256, 4)
__global__ void edge_mfma_k(const int* __restrict__ offs, const int* __restrict__ csr,
                            const float* __restrict__ ws, int l,
                            const float* __restrict__ h, const _Float16* __restrict__ hA,
                            const _Float16* __restrict__ hB, float* __restrict__ hnext,
                            _Float16* __restrict__ hAout, _Float16* __restrict__ hBout,
                            int doNext) {
    __shared__ float vbuf[4 * 256];   // per-wave [8 nodes][32 ch], XOR-swizzled
    const int lane = threadIdx.x & 63;
    const int wid = (blockIdx.x * 256 + threadIdx.x) >> 6;
    const int r = lane & 15;   // A row (edge slot) / D col (channel)
    const int q = lane >> 4;   // channel octet / D row quad
    const int ll = lane & 31;
    float* vb = vbuf + (threadIdx.x >> 6) * 256;
    const int nbase = wid * NPW;
    if (nbase >= N_NODES) return;   // 50000 % 8 == 0 -> full waves only

    // wave-uniform segment bounds -> SGPRs
    int o[NPW + 1];
#pragma unroll
    for (int i = 0; i <= NPW; ++i)
        o[i] = __builtin_amdgcn_readfirstlane(offs[nbase + i]);

    const _Float16* W2H = (const _Float16*)(ws + W2H_OFF);
    f16x8 b0, b1;
#pragma unroll
    for (int i = 0; i < 8; ++i) {
        b0[i] = W2H[l * 1024 + (8 * q + i) * 32 + r];
        b1[i] = W2H[l * 1024 + (8 * q + i) * 32 + 16 + r];
    }
    const float c2a = ws[C2_OFF + l * 32 + r];
    const float c2b = ws[C2_OFF + l * 32 + 16 + r];
    const f32x4 zc0 = {c2a, c2a, c2a, c2a};
    const f32x4 zc1 = {c2b, c2b, c2b, c2b};
    const f16x8 we = *(const f16x8*)((const _Float16*)(ws + WEH_OFF) + l * 32 + 8 * q);
    const f16x8 zero8 = {};

#define CEI(EB, LIM) ({ int _e = (EB) + r; _e = (_e < (LIM)) ? _e : (LIM); _e = (_e > 0) ? _e : 0; _e; })

    // prologue: issue chunk-0 csr, chunk-0 gathers, chunk-1 csr for ALL 4 pairs
    int lim[NPW];
#pragma unroll
    for (int s = 0; s < NPW; ++s) {
        int e1 = o[s + 1] - 1;
        lim[s] = (e1 > 0) ? e1 : 0;
    }
    int pc[NPW], pn[NPW];
#pragma unroll
    for (int s = 0; s < NPW; ++s) pc[s] = csr[CEI(o[s], lim[s])];
    f16x8 hc[NPW];
#pragma unroll
    for (int s = 0; s < NPW; ++s)
        hc[s] = *(const f16x8*)(hB + (pc[s] & 0xFFFF) * 32 + 8 * q);
#pragma unroll
    for (int s = 0; s < NPW; ++s) pn[s] = csr[CEI(o[s] + 16, lim[s])];

#pragma unroll
    for (int p = 0; p < 4; ++p) {
        const int s0 = 2 * p, s1 = 2 * p + 1;
        const int n0 = nbase + s0;
        const int n1 = n0 + 1;
        const int o0 = o[s0], o1 = o[s1], o2 = o[s1 + 1];

        const f16x8 hA0 = *(const f16x8*)(hA + n0 * 32 + 8 * q);
        const f16x8 hA1 = *(const f16x8*)(hA + n1 * 32 + 8 * q);

        float ns00 = 0.f, ns01 = 0.f, ns10 = 0.f, ns11 = 0.f;
        int nit = (o1 - o0 + 15) >> 4;
        int nit1 = (o2 - o1 + 15) >> 4;
        if (nit1 > nit) nit = nit1;

        if (nit > 0) {
            const int lim0 = lim[s0], lim1 = lim[s1];
            int eb0 = o0, eb1 = o1;
            int pc0 = pc[s0], pc1 = pc[s1];
            f16x8 hc0 = hc[s0], hc1 = hc[s1];
            int pn0 = pn[s0], pn1 = pn[s1];
            for (int it = 0; it < nit; ++it) {
                f16x8 hn0 = *(const f16x8*)(hB + (pn0 & 0xFFFF) * 32 + 8 * q);
                f16x8 hn1 = *(const f16x8*)(hB + (pn1 & 0xFFFF) * 32 + 8 * q);
                int pm0 = csr[CEI(eb0 + 32, lim0)];
                int pm1 = csr[CEI(eb1 + 32, lim1)];
                __builtin_amdgcn_s_setprio(1);
                _Float16 eah0 = h16((unsigned short)((unsigned)pc0 >> 16));
                _Float16 eah1 = h16((unsigned short)((unsigned)pc1 >> 16));
                f16x8 a0 = __builtin_elementwise_max(we * eah0 + (hA0 + hc0), zero8);
                f16x8 a1 = __builtin_elementwise_max(we * eah1 + (hA1 + hc1), zero8);
                f32x4 acc00 = __builtin_amdgcn_mfma_f32_16x16x32_f16(a0, b0, zc0, 0, 0, 0);
                f32x4 acc01 = __builtin_amdgcn_mfma_f32_16x16x32_f16(a0, b1, zc1, 0, 0, 0);
                f32x4 acc10 = __builtin_amdgcn_mfma_f32_16x16x32_f16(a1, b0, zc0, 0, 0, 0);
                f32x4 acc11 = __builtin_amdgcn_mfma_f32_16x16x32_f16(a1, b1, zc1, 0, 0, 0);
                int nr0 = o1 - eb0;
                int nr1 = o2 - eb1;
#pragma unroll
                for (int reg = 0; reg < 4; ++reg) {
                    int row = 4 * q + reg;
                    float m0 = (row < nr0) ? 1.f : 0.f;
                    float m1 = (row < nr1) ? 1.f : 0.f;
                    ns00 = fmaf(m0, fmaxf(acc00[reg], 0.f), ns00);
                    ns01 = fmaf(m0, fmaxf(acc01[reg], 0.f), ns01);
                    ns10 = fmaf(m1, fmaxf(acc10[reg], 0.f), ns10);
                    ns11 = fmaf(m1, fmaxf(acc11[reg], 0.f), ns11);
                }
                __builtin_amdgcn_s_setprio(0);
                eb0 += 16; eb1 += 16;
                pc0 = pn0; pc1 = pn1;
                hc0 = hn0; hc1 = hn1;
                pn0 = pm0; pn1 = pm1;
            }
        }
        ns00 += __shfl_xor(ns00, 16, 64);
        ns00 += __shfl_xor(ns00, 32, 64);
        ns01 += __shfl_xor(ns01, 16, 64);
        ns01 += __shfl_xor(ns01, 32, 64);
        ns10 += __shfl_xor(ns10, 16, 64);
        ns10 += __shfl_xor(ns10, 32, 64);
        ns11 += __shfl_xor(ns11, 16, 64);
        ns11 += __shfl_xor(ns11, 32, 64);

        float v;
        if (lane < 32) {
            v = h[n0 * 32 + ll] + ((ll & 16) ? ns01 : ns00);
            hnext[n0 * 32 + ll] = v;
        } else {
            v = h[n1 * 32 + ll] + ((ll & 16) ? ns11 : ns10);
            hnext[n1 * 32 + ll] = v;
        }
        int node8 = s0 + (lane >> 5);                 // 0..7
        vb[node8 * 32 + (ll ^ (node8 << 2))] = v;     // XOR swizzle, conflict-free
    }
#undef CEI

    // epilogue: next layer's hA/hB via 4 MFMAs (wave-private LDS, in-order DS, no barrier)
    if (doNext) {
        const int lw = l + 1;
        f16x8 av;
#pragma unroll
        for (int i = 0; i < 8; ++i) {
            int rr = r & 7;
            int ch = 8 * q + i;
            float vv = vb[rr * 32 + (ch ^ (rr << 2))];
            av[i] = (r < 8) ? (_Float16)vv : (_Float16)0.f;
        }
        const _Float16* W1AH = (const _Float16*)(ws + W1AH_OFF) + lw * 1024;
        const _Float16* W1BH = (const _Float16*)(ws + W1BH_OFF) + lw * 1024;
        f16x8 wa0, wa1, wb0, wb1;
#pragma unroll
        for (int i = 0; i < 8; ++i) {
            wa0[i] = W1AH[(8 * q + i) * 32 + r];
            wa1[i] = W1AH[(8 * q + i) * 32 + 16 + r];
            wb0[i] = W1BH[(8 * q + i) * 32 + r];
            wb1[i] = W1BH[(8 * q + i) * 32 + 16 + r];
        }
        const float c1a = ws[C1_OFF + lw * 32 + r];
        const float c1b = ws[C1_OFF + lw * 32 + 16 + r];
        const f32x4 ca = {c1a, c1a, c1a, c1a};
        const f32x4 cb = {c1b, c1b, c1b, c1b};
        const f32x4 z4 = {0.f, 0.f, 0.f, 0.f};
        f32x4 dA0 = __builtin_amdgcn_mfma_f32_16x16x32_f16(av, wa0, ca, 0, 0, 0);
        f32x4 dA1 = __builtin_amdgcn_mfma_f32_16x16x32_f16(av, wa1, cb, 0, 0, 0);
        f32x4 dB0 = __builtin_amdgcn_mfma_f32_16x16x32_f16(av, wb0, z4, 0, 0, 0);
        f32x4 dB1 = __builtin_amdgcn_mfma_f32_16x16x32_f16(av, wb1, z4, 0, 0, 0);
#pragma unroll
        for (int reg = 0; reg < 4; ++reg) {
            int row = 4 * q + reg;   // node index within wave (valid 0..7)
            int n = nbase + row;
            if (row < 8 && n < N_NODES) {
                hAout[n * 32 + r]      = (_Float16)dA0[reg];
                hAout[n * 32 + 16 + r] = (_Float16)dA1[reg];
                hBout[n * 32 + r]      = (_Float16)dB0[reg];
                hBout[n * 32 + 16 + r] = (_Float16)dB1[reg];
            }
        }
    }
}

__global__ void head_k(const float* __restrict__ h, const int* __restrict__ cand,
                       const int* __restrict__ batch, const float* __restrict__ Wout,
                       const float* __restrict__ bout, float* __restrict__ out) {
    __shared__ float Lg[N_CAND];
    __shared__ int Sg[N_CAND];
    __shared__ float gm[N_GRAPHS], gs[N_GRAPHS];
    int t = threadIdx.x;  // 1024
    if (t < N_CAND) {
        int c = cand[t];
        float acc = bout[0];
#pragma unroll
        for (int j = 0; j < 32; ++j) acc += h[c * 32 + j] * Wout[j];
        Lg[t] = acc;
        Sg[t] = batch[c];
    }
    __syncthreads();
    if (t < 16 * N_GRAPHS) {
        int g = t >> 4, s = t & 15;
        float m = -1e30f;
        for (int i = s; i < N_CAND; i += 16)
            if (Sg[i] == g) m = fmaxf(m, Lg[i]);
#pragma unroll
        for (int d = 1; d < 16; d <<= 1) m = fmaxf(m, __shfl_xor(m, d, 64));
        float ssum = 0.f;
        for (int i = s; i < N_CAND; i += 16)
            if (Sg[i] == g) ssum += expf(Lg[i] - m);
#pragma unroll
        for (int d = 1; d < 16; d <<= 1) ssum += __shfl_xor(ssum, d, 64);
        if (s == 0) { gm[g] = m; gs[g] = logf(ssum); }
    }
    __syncthreads();
    if (t < N_CAND) out[t] = Lg[t] - gm[Sg[t]] - gs[Sg[t]];
}

extern "C" void kernel_launch(void* const* d_in, const int* in_sizes, int n_in,
                              void* d_out, int out_size, void* d_ws, size_t ws_size,
                              hipStream_t stream) {
    const float* x    = (const float*)d_in[0];
    const int*   ei   = (const int*)d_in[1];
    const float* eatt = (const float*)d_in[2];
    const int*   cand = (const int*)d_in[3];
    const int*   batch= (const int*)d_in[4];
    const float* Win  = (const float*)d_in[5];
    const float* bin  = (const float*)d_in[6];
    const float* W1   = (const float*)d_in[7];
    const float* b1   = (const float*)d_in[8];
    const float* g1   = (const float*)d_in[9];
    const float* be1  = (const float*)d_in[10];
    const float* m1   = (const float*)d_in[11];
    const float* v1   = (const float*)d_in[12];
    const float* W2   = (const float*)d_in[13];
    const float* b2   = (const float*)d_in[14];
    const float* g2   = (const float*)d_in[15];
    const float* be2  = (const float*)d_in[16];
    const float* m2   = (const float*)d_in[17];
    const float* v2   = (const float*)d_in[18];
    const float* Wout = (const float*)d_in[19];
    const float* bout = (const float*)d_in[20];
    float* out = (float*)d_out;
    float* ws = (float*)d_ws;

    float* h0 = ws + H_OFF;
    float* h1 = ws + H_OFF + NODE_F;
    _Float16* hA0 = (_Float16*)(ws + H_OFF + 2 * NODE_F);
    _Float16* hB0 = (_Float16*)(ws + H_OFF + 2 * NODE_F + NODE_F / 2);
    _Float16* hA1 = (_Float16*)(ws + H_OFF + 3 * NODE_F);
    _Float16* hB1 = (_Float16*)(ws + H_OFF + 3 * NODE_F + NODE_F / 2);
    int* bh    = (int*)(ws + BH_OFF);
    int* boffs = (int*)(ws + BOFF_OFF);
    int* offs  = (int*)(ws + OFFS_OFF);
    int* csr   = (int*)(ws + CSR_OFF);
    int* T     = (int*)(ws + T_OFF);
    int2* stage = (int2*)(ws + H_OFF + NODE_F);  // aliases h1+hA0/hB0 (pre-embed only)

    prep_bhist_k<<<NBLK_S, 512, 0, stream>>>(W1, b1, g1, be1, m1, v1,
                                             W2, b2, g2, be2, m2, v2, ws, ei, T);
    bcursor_k<<<NBK, 1024, 0, stream>>>(T, bh);
    bscan_k<<<1, 1024, 0, stream>>>(bh, boffs);
    bscatter_k<<<NBLK_S, 512, 0, stream>>>(ei, eatt, T, boffs, stage);
    bsort2_k<<<NBK, 512, 0, stream>>>(boffs, stage, offs, csr);

    // embed + layer-0 node transform (after stage's aliased region is consumed)
    embed_node_k<<<(NODE_F + 1023) / 1024, 1024, 0, stream>>>(x, Win, bin, ws, h0, hA0, hB0);

    const int waves = (N_NODES + NPW - 1) / NPW;       // 6250
    const int eblocks = (waves + 3) / 4;               // 1563
    float* cur = h0;
    float* nxt = h1;
    _Float16 *cA = hA0, *cB = hB0, *nA = hA1, *nB = hB1;
    for (int l = 0; l < L_LAYERS; ++l) {
        edge_mfma_k<<<eblocks, 256, 0, stream>>>(offs, csr, ws, l, cur, cA, cB,
                                                 nxt, nA, nB, l < L_LAYERS - 1);
        float* tf = cur; cur = nxt; nxt = tf;
        _Float16* t1 = cA; cA = nA; nA = t1;
        _Float16* t2 = cB; cB = nB; nB = t2;
    }

    head_k<<<1, 1024, 0, stream>>>(cur, cand, batch, Wout, bout, out);
}